// Round 1
// baseline (50.972 us; speedup 1.0000x reference)
//
#include <hip/hip_runtime.h>

// Problem constants (fixed by setup_inputs)
#define B0_   2
#define B1_   4
#define C_    64
#define HH    32
#define WW    32
#define P_    1024          // H*W
#define KLEN  9
#define S_    8
#define N1_   36            // B1*KLEN
#define WP    34            // W + 2*pad
#define SPLIT 16            // split of the 128 (b0,c) pairs
#define BCPB  8             // (B0_*C_)/SPLIT pairs per block
#define THREADS 256

__device__ __forceinline__ void block_reduce_atomic(float acc[8], int n1,
                                                    float* __restrict__ out) {
    __shared__ float red[4][8];
    int tid = threadIdx.x;
    int lane = tid & 63, wid = tid >> 6;
#pragma unroll
    for (int s = 0; s < 8; ++s) {
        float v = acc[s];
#pragma unroll
        for (int off = 32; off >= 1; off >>= 1) v += __shfl_down(v, off, 64);
        if (lane == 0) red[wid][s] = v;
    }
    __syncthreads();
    if (tid < 8) {
        float t = red[0][tid] + red[1][tid] + red[2][tid] + red[3][tid];
        atomicAdd(&out[n1 * 8 + tid], t);
    }
}

// Decode the 4 p-positions this thread owns (p = tid + j*256) into x-plane offsets.
__device__ __forceinline__ void decode_offsets(const int* __restrict__ indexm,
                                               int k, int tid, int offhw[4]) {
#pragma unroll
    for (int j = 0; j < 4; ++j) {
        int p = tid + j * THREADS;
        int idx = indexm[k * P_ + p];     // index into flattened 34x34 padded map
        int r  = idx / WP;
        int cc = idx - r * WP;
        int ir = r - 1, ic = cc - 1;      // un-pad
        offhw[j] = (ir >= 0 && ir < HH && ic >= 0 && ic < WW) ? ir * WW + ic : -1;
    }
}

// Pass 1: v_pre1 = sum over (b0,c,p) of g * W   (uniform coupling applied later)
__global__ __launch_bounds__(THREADS)
void pass_uniform(const float* __restrict__ x, const float* __restrict__ wgt,
                  const int* __restrict__ indexm, float* __restrict__ accOut) {
    int split = blockIdx.x;
    int n1 = blockIdx.y;
    int tid = threadIdx.x;
    int k = n1 % KLEN, b1 = n1 / KLEN;

    int offhw[4];
    decode_offsets(indexm, k, tid, offhw);

    float acc[8] = {0.f,0.f,0.f,0.f,0.f,0.f,0.f,0.f};
    for (int bc = split * BCPB; bc < split * BCPB + BCPB; ++bc) {
        int b0 = bc >> 6, c = bc & 63;
        const float* xc = x + ((((b0 << 2) + b1) << 6) + c) * P_;
        const float* wc = wgt + c * (KLEN * S_) + k * S_;
        float w[8];
#pragma unroll
        for (int s = 0; s < 8; ++s) w[s] = wc[s];
#pragma unroll
        for (int j = 0; j < 4; ++j) {
            float g = (offhw[j] >= 0) ? xc[offhw[j]] : 0.f;
#pragma unroll
            for (int s = 0; s < 8; ++s) acc[s] += g * w[s];
        }
    }
    block_reduce_atomic(acc, n1, accOut);
}

// Pass 2/3: vprev = squash(aPrev*scale); accumulate sum of u * softmax_s(u*vprev)
__global__ __launch_bounds__(THREADS)
void pass_route(const float* __restrict__ x, const float* __restrict__ wgt,
                const int* __restrict__ indexm, const float* __restrict__ aPrev,
                float prevScale, float* __restrict__ accOut) {
    int split = blockIdx.x;
    int n1 = blockIdx.y;
    int tid = threadIdx.x;
    int k = n1 % KLEN, b1 = n1 / KLEN;

    // Redundant per-thread squash of previous accumulator (8 cached loads)
    float vp[8]; float n2 = 0.f;
#pragma unroll
    for (int s = 0; s < 8; ++s) {
        float t = aPrev[n1 * 8 + s] * prevScale;
        vp[s] = t; n2 += t * t;
    }
    float f = (n2 / (1.f + n2)) * rsqrtf(n2 + 1e-8f);
#pragma unroll
    for (int s = 0; s < 8; ++s) vp[s] *= f;

    int offhw[4];
    decode_offsets(indexm, k, tid, offhw);

    float acc[8] = {0.f,0.f,0.f,0.f,0.f,0.f,0.f,0.f};
    for (int bc = split * BCPB; bc < split * BCPB + BCPB; ++bc) {
        int b0 = bc >> 6, c = bc & 63;
        const float* xc = x + ((((b0 << 2) + b1) << 6) + c) * P_;
        const float* wc = wgt + c * (KLEN * S_) + k * S_;
        float w[8], wv[8];
#pragma unroll
        for (int s = 0; s < 8; ++s) { w[s] = wc[s]; wv[s] = w[s] * vp[s]; }
#pragma unroll
        for (int j = 0; j < 4; ++j) {
            float g = (offhw[j] >= 0) ? xc[offhw[j]] : 0.f;
            float b[8]; float m = -1e30f;
#pragma unroll
            for (int s = 0; s < 8; ++s) { b[s] = g * wv[s]; m = fmaxf(m, b[s]); }
            float e[8]; float Z = 0.f;
#pragma unroll
            for (int s = 0; s < 8; ++s) { e[s] = __expf(b[s] - m); Z += e[s]; }
            float sc = g / Z;  // u_s*c_s = (g*w_s)*(e_s/Z)
#pragma unroll
            for (int s = 0; s < 8; ++s) acc[s] += sc * w[s] * e[s];
        }
    }
    block_reduce_atomic(acc, n1, accOut);
}

__global__ void finalize_out(const float* __restrict__ a3, float* __restrict__ out) {
    int tid = threadIdx.x;
    if (tid < N1_) {
        float v[8]; float n2 = 0.f;
#pragma unroll
        for (int s = 0; s < 8; ++s) {
            float t = a3[tid * 8 + s];
            v[s] = t; n2 += t * t;
        }
        float f = (n2 / (1.f + n2)) * rsqrtf(n2 + 1e-8f);
#pragma unroll
        for (int s = 0; s < 8; ++s) out[tid * 8 + s] = v[s] * f * 0.5f + 0.5f;
    }
}

extern "C" void kernel_launch(void* const* d_in, const int* in_sizes, int n_in,
                              void* d_out, int out_size, void* d_ws, size_t ws_size,
                              hipStream_t stream) {
    const float* x    = (const float*)d_in[0];
    const float* wgt  = (const float*)d_in[1];
    const int*   idxm = (const int*)d_in[2];
    float* ws = (float*)d_ws;
    float* A1 = ws;
    float* A2 = ws + N1_ * S_;
    float* A3 = ws + 2 * N1_ * S_;

    // Zero the three accumulator banks every call (graph replays include this).
    hipMemsetAsync(d_ws, 0, 3 * N1_ * S_ * sizeof(float), stream);

    dim3 grid(SPLIT, N1_);
    pass_uniform<<<grid, THREADS, 0, stream>>>(x, wgt, idxm, A1);
    pass_route <<<grid, THREADS, 0, stream>>>(x, wgt, idxm, A1, 0.125f, A2);
    pass_route <<<grid, THREADS, 0, stream>>>(x, wgt, idxm, A2, 1.0f,   A3);
    finalize_out<<<1, 64, 0, stream>>>(A3, (float*)d_out);
}

// Round 2
// 41.558 us; speedup vs baseline: 1.2265x; 1.2265x over previous
//
#include <hip/hip_runtime.h>

// Problem constants (fixed by setup_inputs)
#define B0_   2
#define B1_   4
#define C_    64
#define HH    32
#define WW    32
#define P_    1024          // H*W
#define KLEN  9
#define S_    8
#define N1_   36            // B1*KLEN
#define WP    34            // W + 2*pad
#define SPLIT 16            // split of the 128 (b0,c) pairs
#define BCPB  8             // (B0_*C_)/SPLIT pairs per block
#define THREADS 256

// Block-reduce acc[8] across 256 threads, then STORE the block partial to
// out[(n1*SPLIT+split)*8 + s]. No atomics -> no zeroing -> no memset.
__device__ __forceinline__ void block_reduce_store(float acc[8], int n1, int split,
                                                   float* __restrict__ out) {
    __shared__ float red[4][8];
    int tid = threadIdx.x;
    int lane = tid & 63, wid = tid >> 6;
#pragma unroll
    for (int s = 0; s < 8; ++s) {
        float v = acc[s];
#pragma unroll
        for (int off = 32; off >= 1; off >>= 1) v += __shfl_down(v, off, 64);
        if (lane == 0) red[wid][s] = v;
    }
    __syncthreads();
    if (tid < 8) {
        float t = red[0][tid] + red[1][tid] + red[2][tid] + red[3][tid];
        out[(n1 * SPLIT + split) * 8 + tid] = t;
    }
}

// Decode the 4 p-positions this thread owns (p = tid + j*256) into x-plane offsets.
__device__ __forceinline__ void decode_offsets(const int* __restrict__ indexm,
                                               int k, int tid, int offhw[4]) {
#pragma unroll
    for (int j = 0; j < 4; ++j) {
        int p = tid + j * THREADS;
        int idx = indexm[k * P_ + p];     // index into flattened 34x34 padded map
        int r  = idx / WP;
        int cc = idx - r * WP;
        int ir = r - 1, ic = cc - 1;      // un-pad
        offhw[j] = (ir >= 0 && ir < HH && ic >= 0 && ic < WW) ? ir * WW + ic : -1;
    }
}

// Pass 1: partials of sum over (b0,c,p) of g * W  (uniform coupling folded in later)
__global__ __launch_bounds__(THREADS)
void pass_uniform(const float* __restrict__ x, const float* __restrict__ wgt,
                  const int* __restrict__ indexm, float* __restrict__ partOut) {
    int split = blockIdx.x;
    int n1 = blockIdx.y;
    int tid = threadIdx.x;
    int k = n1 % KLEN, b1 = n1 / KLEN;

    int offhw[4];
    decode_offsets(indexm, k, tid, offhw);

    float acc[8] = {0.f,0.f,0.f,0.f,0.f,0.f,0.f,0.f};
    for (int bc = split * BCPB; bc < split * BCPB + BCPB; ++bc) {
        int b0 = bc >> 6, c = bc & 63;
        const float* xc = x + ((((b0 << 2) + b1) << 6) + c) * P_;
        const float* wc = wgt + c * (KLEN * S_) + k * S_;
        float w[8];
#pragma unroll
        for (int s = 0; s < 8; ++s) w[s] = wc[s];
#pragma unroll
        for (int j = 0; j < 4; ++j) {
            float g = (offhw[j] >= 0) ? xc[offhw[j]] : 0.f;
#pragma unroll
            for (int s = 0; s < 8; ++s) acc[s] += g * w[s];
        }
    }
    block_reduce_store(acc, n1, split, partOut);
}

// Pass 2/3: vprev = squash(sum(prev partials)*scale);
// partials of sum over (b0,c,p) of u * softmax_s(u*vprev)
__global__ __launch_bounds__(THREADS)
void pass_route(const float* __restrict__ x, const float* __restrict__ wgt,
                const int* __restrict__ indexm, const float* __restrict__ partPrev,
                float prevScale, float* __restrict__ partOut) {
    int split = blockIdx.x;
    int n1 = blockIdx.y;
    int tid = threadIdx.x;
    int k = n1 % KLEN, b1 = n1 / KLEN;

    // Sum the 16 previous-pass partials (uniform addresses; L2-hot), then squash.
    float vp[8] = {0.f,0.f,0.f,0.f,0.f,0.f,0.f,0.f};
#pragma unroll
    for (int i = 0; i < SPLIT; ++i) {
        const float* pp = partPrev + (n1 * SPLIT + i) * 8;
#pragma unroll
        for (int s = 0; s < 8; ++s) vp[s] += pp[s];
    }
    float n2 = 0.f;
#pragma unroll
    for (int s = 0; s < 8; ++s) { vp[s] *= prevScale; n2 += vp[s] * vp[s]; }
    float f = (n2 / (1.f + n2)) * rsqrtf(n2 + 1e-8f);
#pragma unroll
    for (int s = 0; s < 8; ++s) vp[s] *= f;

    int offhw[4];
    decode_offsets(indexm, k, tid, offhw);

    float acc[8] = {0.f,0.f,0.f,0.f,0.f,0.f,0.f,0.f};
    for (int bc = split * BCPB; bc < split * BCPB + BCPB; ++bc) {
        int b0 = bc >> 6, c = bc & 63;
        const float* xc = x + ((((b0 << 2) + b1) << 6) + c) * P_;
        const float* wc = wgt + c * (KLEN * S_) + k * S_;
        float w[8], wv[8];
#pragma unroll
        for (int s = 0; s < 8; ++s) { w[s] = wc[s]; wv[s] = w[s] * vp[s]; }
#pragma unroll
        for (int j = 0; j < 4; ++j) {
            float g = (offhw[j] >= 0) ? xc[offhw[j]] : 0.f;
            // |g*wv| < ~0.5 -> softmax without max-subtraction is safe.
            float e[8]; float Z = 0.f;
#pragma unroll
            for (int s = 0; s < 8; ++s) { e[s] = __expf(g * wv[s]); Z += e[s]; }
            float sc = g * __builtin_amdgcn_rcpf(Z);  // u_s*c_s = (g*w_s)*(e_s/Z)
#pragma unroll
            for (int s = 0; s < 8; ++s) acc[s] += sc * w[s] * e[s];
        }
    }
    block_reduce_store(acc, n1, split, partOut);
}

__global__ void finalize_out(const float* __restrict__ part3, float* __restrict__ out) {
    int tid = threadIdx.x;
    if (tid < N1_) {
        float v[8] = {0.f,0.f,0.f,0.f,0.f,0.f,0.f,0.f};
#pragma unroll
        for (int i = 0; i < SPLIT; ++i) {
            const float* pp = part3 + (tid * SPLIT + i) * 8;
#pragma unroll
            for (int s = 0; s < 8; ++s) v[s] += pp[s];
        }
        float n2 = 0.f;
#pragma unroll
        for (int s = 0; s < 8; ++s) n2 += v[s] * v[s];
        float f = (n2 / (1.f + n2)) * rsqrtf(n2 + 1e-8f);
#pragma unroll
        for (int s = 0; s < 8; ++s) out[tid * 8 + s] = v[s] * f * 0.5f + 0.5f;
    }
}

extern "C" void kernel_launch(void* const* d_in, const int* in_sizes, int n_in,
                              void* d_out, int out_size, void* d_ws, size_t ws_size,
                              hipStream_t stream) {
    const float* x    = (const float*)d_in[0];
    const float* wgt  = (const float*)d_in[1];
    const int*   idxm = (const int*)d_in[2];
    float* ws = (float*)d_ws;
    const int PBANK = N1_ * SPLIT * S_;   // 4608 floats per pass
    float* P1 = ws;
    float* P2 = ws + PBANK;
    float* P3 = ws + 2 * PBANK;

    dim3 grid(SPLIT, N1_);
    pass_uniform<<<grid, THREADS, 0, stream>>>(x, wgt, idxm, P1);
    pass_route <<<grid, THREADS, 0, stream>>>(x, wgt, idxm, P1, 0.125f, P2);
    pass_route <<<grid, THREADS, 0, stream>>>(x, wgt, idxm, P2, 1.0f,   P3);
    finalize_out<<<1, 64, 0, stream>>>(P3, (float*)d_out);
}